// Round 4
// baseline (1847.372 us; speedup 1.0000x reference)
//
#include <hip/hip_runtime.h>
#include <hip/hip_bf16.h>

// ============================================================================
// TransformerChoiceNet forward. Round 18: GEMM family 128x256 tiles with
// 512-thread (8-wave) blocks — per-wave acc stays 16 frags (r2 geometry),
// LDS 48KB -> 3 blocks/CU (24 waves/CU vs r3's 8). Staging calls/wave/K-step
// 10 -> 6. k_qkv / k_attn unchanged from r16.
// B=128 S=512 D=64 H=256 NH=8 HD=32, M=B*S=65536.
// ============================================================================

#define Bb  128
#define Ss  512
#define Hh  256
#define NHh 8
#define Mm  (Bb*Ss)

typedef unsigned short bf16_t;
typedef __attribute__((ext_vector_type(8))) short short8;
typedef __attribute__((ext_vector_type(4))) float f32x4;

__device__ __forceinline__ float bf2f(bf16_t h){
  union { unsigned int u; float f; } v; v.u = ((unsigned int)h)<<16; return v.f;
}
__device__ __forceinline__ bf16_t f2bf(float f){
  union { float f; unsigned int u; } v; v.f = f;
  unsigned int r = (v.u + 0x7fffu + ((v.u>>16)&1u)) >> 16;   // RNE
  return (bf16_t)r;
}
__device__ __forceinline__ unsigned pk_bf16(float a, float b){  // packed RNE cvt
  union { __hip_bfloat162 h; unsigned u; } v;
  v.h = __float22bfloat162_rn(float2{a,b});
  return v.u;
}
__device__ __forceinline__ short8 ld_bf8(const bf16_t* p){   // 16B load
  union { uint4 u; short8 s; } v; v.u = *(const uint4*)p; return v.s;
}
__device__ __forceinline__ void gload16(const bf16_t* g, bf16_t* l){
  __builtin_amdgcn_global_load_lds(
      (const __attribute__((address_space(1))) void*)g,
      (__attribute__((address_space(3))) void*)l, 16, 0, 0);
}
__device__ __forceinline__ float exp2_hw(float x){           // native 2^x
  float r; asm("v_exp_f32 %0, %1" : "=v"(r) : "v"(x)); return r;
}
__device__ __forceinline__ float gelu_f(float x){
  // NewGELU; tanh via native exp + rcp: tanh(u) = 1 - 2/(e^{2u}+1)
  float u = 0.7978845608028654f*(x + 0.044715f*x*x*x);
  float e = __expf(2.0f*u);
  float th = 1.0f - 2.0f*__builtin_amdgcn_rcpf(e + 1.0f);
  return 0.5f*x*(1.0f + th);
}

// ---------------- weight prep: fp32 W[k][n] -> bf16 Wt[n][k] ------------------
struct PrepDesc { const float* s; unsigned off; int K; };
struct Prep18  { PrepDesc d[18]; };

__global__ __launch_bounds__(256) void k_prep(Prep18 p, bf16_t* __restrict__ arena)
{
  PrepDesc dd = p.d[blockIdx.y];
  int i = blockIdx.x*256 + threadIdx.x;
  if (i < dd.K*256){
    int k = i>>8, n = i&255;
    arena[dd.off + n*dd.K + k] = f2bf(dd.s[i]);
  }
}

// ---------------- LN0 (two gains) + valid mask; bf16 out ----------------------
__global__ __launch_bounds__(256) void k_ln0(const float* __restrict__ src,
    const float* __restrict__ gs, const float* __restrict__ bs,
    const float* __restrict__ gt, const float* __restrict__ bt,
    bf16_t* __restrict__ xs, bf16_t* __restrict__ xt, float* __restrict__ valid)
{
  int row  = blockIdx.x*4 + (threadIdx.x>>6);
  int lane = threadIdx.x & 63;
  float x = src[(size_t)row*64 + lane];
  float s = x;
  #pragma unroll
  for (int o=32;o>0;o>>=1) s += __shfl_xor(s,o);
  float mean = s*(1.0f/64.0f);
  float d = x - mean;
  float ss = d*d;
  #pragma unroll
  for (int o=32;o>0;o>>=1) ss += __shfl_xor(ss,o);
  float r = rsqrtf(ss*(1.0f/64.0f) + 1e-5f);
  float xn = d*r;
  xs[(size_t)row*64+lane] = f2bf(xn*gs[lane] + bs[lane]);
  xt[(size_t)row*64+lane] = f2bf(xn*gt[lane] + bt[lane]);
  if (lane==0) valid[row] = (s != 0.0f) ? 1.0f : 0.0f;
}

// ---------------- merged independent GEMMs, 128-row / 8-wave blocks -----------
struct GemmJob  { const bf16_t* A; const bf16_t* Wt; const float* bias; bf16_t* C;
                  int outm; float cs; };
struct GemmJobs { GemmJob j[3]; };

template<int KK>
__global__ __launch_bounds__(512,6) void k_gemm3(GemmJobs jobs)
{
  __shared__ bf16_t As[16*512];   // 16 KB: id = h*8 + kc32*4 + mt
  __shared__ bf16_t Bs[32*512];   // 32 KB: id = kc32*16 + gnt
  GemmJob jb = jobs.j[blockIdx.y];
  int t = threadIdx.x, w = t>>6, lane = t&63, l15 = lane&15, quad = lane>>4;
  int wh = w>>2, wn = w&3;
  int m0 = blockIdx.x*128;
  f32x4 z = {0.f,0.f,0.f,0.f};
  f32x4 acc[4][4] = {{z,z,z,z},{z,z,z,z},{z,z,z,z},{z,z,z,z}};

  #pragma unroll
  for (int k0=0; k0<KK; k0+=64){
    #pragma unroll
    for (int j=0; j<2; j++){
      int id = 2*w + j; int h = id>>3, kc32 = (id>>2)&1, mt = id&3;
      gload16(jb.A + (size_t)(m0 + h*64 + mt*16 + l15)*KK + k0 + kc32*32 + quad*8,
              &As[id*512]);
    }
    #pragma unroll
    for (int j=0; j<4; j++){
      int id = 4*w + j; int kc32 = id>>4, gnt = id&15;
      gload16(jb.Wt + (size_t)(gnt*16 + l15)*KK + k0 + kc32*32 + quad*8,
              &Bs[id*512]);
    }
    __syncthreads();
    #pragma unroll
    for (int kc=0; kc<2; kc++){
      short8 a[4], b[4];
      #pragma unroll
      for (int mt=0; mt<4; mt++) a[mt] = ld_bf8(&As[(wh*8 + kc*4 + mt)*512 + lane*8]);
      #pragma unroll
      for (int nt=0; nt<4; nt++) b[nt] = ld_bf8(&Bs[(kc*16 + wn*4 + nt)*512 + lane*8]);
      #pragma unroll
      for (int mt=0; mt<4; mt++)
        #pragma unroll
        for (int nt=0; nt<4; nt++)
          acc[mt][nt] = __builtin_amdgcn_mfma_f32_16x16x32_bf16(a[mt], b[nt], acc[mt][nt], 0,0,0);
    }
    __syncthreads();
  }

  float bv[4];
  #pragma unroll
  for (int nt=0; nt<4; nt++) bv[nt] = jb.bias[wn*64 + nt*16 + l15];
  float cs = jb.cs;

  if (jb.outm == 0){
    #pragma unroll
    for (int mt=0; mt<4; mt++)
      #pragma unroll
      for (int nt=0; nt<4; nt++){
        int m = m0 + wh*64 + mt*16 + quad*4;
        int col = wn*64 + nt*16 + l15;
        #pragma unroll
        for (int r=0; r<4; r++)
          jb.C[(size_t)(m+r)*256 + col] = f2bf((acc[mt][nt][r] + bv[nt])*cs);
      }
  } else {
    #pragma unroll
    for (int mt=0; mt<4; mt++)
      #pragma unroll
      for (int nt=0; nt<4; nt++){
        int m = m0 + wh*64 + mt*16 + quad*4;
        int col = wn*64 + nt*16 + l15;
        uint2 pk = { pk_bf16(acc[mt][nt][0]+bv[nt], acc[mt][nt][1]+bv[nt]),
                     pk_bf16(acc[mt][nt][2]+bv[nt], acc[mt][nt][3]+bv[nt]) };
        *(uint2*)&jb.C[((size_t)((m>>9)*256 + col))*512 + (m&511)] = pk;
      }
  }
}

// ---------------- fused QKV trio: A staged once, 3 weight loops ---------------
struct QkvJob { const bf16_t* A;
                const bf16_t* Wt0; const bf16_t* Wt1; const bf16_t* Wt2;
                const float* b0; const float* b1; const float* b2;
                bf16_t* C0; bf16_t* C1; bf16_t* C2; float qs; };

__global__ __launch_bounds__(256,2) void k_qkv(QkvJob jb)
{
  __shared__ bf16_t As[32*512];   // 32 KB: full A tile, id = kc32*4 + mt
  __shared__ bf16_t Bs[32*512];   // 32 KB: BK=64 weight tile, id = kc*16 + gnt
  int t = threadIdx.x, w = t>>6, lane = t&63, l15 = lane&15, quad = lane>>4;
  int m0 = blockIdx.x*64;
  f32x4 z = {0.f,0.f,0.f,0.f};

  #pragma unroll
  for (int j=0; j<8; j++){                    // stage FULL A once (8 per wave)
    int id = 8*w + j; int kc32 = id>>2, mt = id&3;
    gload16(jb.A + (size_t)(m0 + mt*16 + l15)*256 + kc32*32 + quad*8,
            &As[id*512]);
  }

  const bf16_t* Wts[3]  = { jb.Wt0, jb.Wt1, jb.Wt2 };
  const float*  bias[3] = { jb.b0,  jb.b1,  jb.b2  };
  bf16_t*       Cs[3]   = { jb.C0,  jb.C1,  jb.C2  };

  #pragma unroll 1
  for (int o=0; o<3; o++){
    const bf16_t* Wt = Wts[o];
    f32x4 acc[4][4] = {{z,z,z,z},{z,z,z,z},{z,z,z,z},{z,z,z,z}};
    #pragma unroll 1
    for (int ki=0; ki<4; ki++){
      #pragma unroll
      for (int j=0; j<8; j++){
        int id = 8*w + j; int kc32 = id>>4, gnt = id&15;
        gload16(Wt + (size_t)(gnt*16 + l15)*256 + ki*64 + kc32*32 + quad*8,
                &Bs[id*512]);
      }
      __syncthreads();                        // drains A stage too (first iter)
      #pragma unroll
      for (int kc=0; kc<2; kc++){
        short8 a[4], b[4];
        #pragma unroll
        for (int mt=0; mt<4; mt++)
          a[mt] = ld_bf8(&As[((ki*2+kc)*4 + mt)*512 + lane*8]);
        #pragma unroll
        for (int nt=0; nt<4; nt++)
          b[nt] = ld_bf8(&Bs[(kc*16 + w*4 + nt)*512 + lane*8]);
        #pragma unroll
        for (int mt=0; mt<4; mt++)
          #pragma unroll
          for (int nt=0; nt<4; nt++)
            acc[mt][nt] = __builtin_amdgcn_mfma_f32_16x16x32_bf16(a[mt], b[nt], acc[mt][nt], 0,0,0);
      }
      __syncthreads();                        // Bs reused next ki / next output
    }
    float bv[4];
    #pragma unroll
    for (int nt=0; nt<4; nt++) bv[nt] = bias[o][w*64 + nt*16 + l15];
    bf16_t* C = Cs[o];
    if (o < 2){                               // Q (scaled) / K: bf16 [M,256]
      float cs = (o==0) ? jb.qs : 1.0f;
      #pragma unroll
      for (int mt=0; mt<4; mt++)
        #pragma unroll
        for (int nt=0; nt<4; nt++){
          int m = m0 + mt*16 + quad*4;
          int col = w*64 + nt*16 + l15;
          #pragma unroll
          for (int r=0; r<4; r++)
            C[(size_t)(m+r)*256 + col] = f2bf((acc[mt][nt][r] + bv[nt])*cs);
        }
    } else {                                  // V -> VT[b][n][s] packed 8B
      #pragma unroll
      for (int mt=0; mt<4; mt++)
        #pragma unroll
        for (int nt=0; nt<4; nt++){
          int m = m0 + mt*16 + quad*4;
          int col = w*64 + nt*16 + l15;
          uint2 pk = { pk_bf16(acc[mt][nt][0]+bv[nt], acc[mt][nt][1]+bv[nt]),
                       pk_bf16(acc[mt][nt][2]+bv[nt], acc[mt][nt][3]+bv[nt]) };
          *(uint2*)&C[((size_t)((m>>9)*256 + col))*512 + (m&511)] = pk;
        }
    }
  }
}

// ---------------- MFMA GEMM, 128-row / 8-wave blocks, fused epilogues ---------
// OUTM: 0 bf16 C[M,256] (EPI 0/1) | 3 LN(Pres+(acc+b)) -> bf16 P |
//       5 like 3 but dot outW -> fp32 logits.
template<int EPI, int OUTM, int KK>
__global__ __launch_bounds__(512,6) void k_gemm(const bf16_t* __restrict__ A,
    const bf16_t* __restrict__ Wt, const float* __restrict__ bias,
    void* __restrict__ Cv, const bf16_t* __restrict__ Pres,
    const float* __restrict__ g, const float* __restrict__ bb,
    const float* __restrict__ oW, const float* __restrict__ obp)
{
  __shared__ bf16_t As[16*512];   // 16 KB: id = h*8 + kc32*4 + mt
  __shared__ bf16_t Bs[32*512];   // 32 KB: id = kc32*16 + gnt
  int t = threadIdx.x, w = t>>6, lane = t&63, l15 = lane&15, quad = lane>>4;
  int wh = w>>2, wn = w&3;
  int m0 = blockIdx.x*128;
  f32x4 z = {0.f,0.f,0.f,0.f};
  f32x4 acc[4][4] = {{z,z,z,z},{z,z,z,z},{z,z,z,z},{z,z,z,z}};

  #pragma unroll
  for (int k0=0; k0<KK; k0+=64){
    #pragma unroll
    for (int j=0; j<2; j++){
      int id = 2*w + j; int h = id>>3, kc32 = (id>>2)&1, mt = id&3;
      gload16(A + (size_t)(m0 + h*64 + mt*16 + l15)*KK + k0 + kc32*32 + quad*8,
              &As[id*512]);
    }
    #pragma unroll
    for (int j=0; j<4; j++){
      int id = 4*w + j; int kc32 = id>>4, gnt = id&15;
      gload16(Wt + (size_t)(gnt*16 + l15)*KK + k0 + kc32*32 + quad*8,
              &Bs[id*512]);
    }
    __syncthreads();
    #pragma unroll
    for (int kc=0; kc<2; kc++){
      short8 a[4], b[4];
      #pragma unroll
      for (int mt=0; mt<4; mt++) a[mt] = ld_bf8(&As[(wh*8 + kc*4 + mt)*512 + lane*8]);
      #pragma unroll
      for (int nt=0; nt<4; nt++) b[nt] = ld_bf8(&Bs[(kc*16 + wn*4 + nt)*512 + lane*8]);
      #pragma unroll
      for (int mt=0; mt<4; mt++)
        #pragma unroll
        for (int nt=0; nt<4; nt++)
          acc[mt][nt] = __builtin_amdgcn_mfma_f32_16x16x32_bf16(a[mt], b[nt], acc[mt][nt], 0,0,0);
    }
    __syncthreads();
  }

  float bv[4];
  #pragma unroll
  for (int nt=0; nt<4; nt++) bv[nt] = bias[wn*64 + nt*16 + l15];

  if (OUTM==0){
    #pragma unroll
    for (int mt=0; mt<4; mt++)
      #pragma unroll
      for (int nt=0; nt<4; nt++)
        #pragma unroll
        for (int r=0; r<4; r++){
          int row = m0 + wh*64 + mt*16 + quad*4 + r;
          int col = wn*64 + nt*16 + l15;
          float v = acc[mt][nt][r] + bv[nt];
          if (EPI==1) v = gelu_f(v);
          ((bf16_t*)Cv)[(size_t)row*256 + col] = f2bf(v);
        }
  } else {
    float* RedS = (float*)As;          // [128][4]
    float* RedQ = RedS + 512;          // [128][4]
    #pragma unroll
    for (int mt=0; mt<4; mt++)
      #pragma unroll
      for (int r=0; r<4; r++){
        int rr = wh*64 + mt*16 + quad*4 + r;
        int row = m0 + rr;
        const bf16_t* pr = Pres + (size_t)row*256;
        float s = 0.f, q = 0.f;
        #pragma unroll
        for (int nt=0; nt<4; nt++){
          float v = acc[mt][nt][r] + bv[nt] + bf2f(pr[wn*64 + nt*16 + l15]);
          s += v; q += v*v;
        }
        s += __shfl_xor(s,1); s += __shfl_xor(s,2);
        s += __shfl_xor(s,4); s += __shfl_xor(s,8);
        q += __shfl_xor(q,1); q += __shfl_xor(q,2);
        q += __shfl_xor(q,4); q += __shfl_xor(q,8);
        if (l15==0){ RedS[rr*4 + wn] = s; RedQ[rr*4 + wn] = q; }
      }
    __syncthreads();

    float gv[4], bbv[4], wv[4];
    #pragma unroll
    for (int nt=0; nt<4; nt++){ gv[nt] = g[wn*64+nt*16+l15]; bbv[nt] = bb[wn*64+nt*16+l15]; }
    if (OUTM==5)
      #pragma unroll
      for (int nt=0; nt<4; nt++) wv[nt] = oW[wn*64+nt*16+l15];

    float s2p[4][4];
    #pragma unroll
    for (int mt=0; mt<4; mt++)
      #pragma unroll
      for (int r=0; r<4; r++){
        int rr = wh*64 + mt*16 + quad*4 + r;
        int row = m0 + rr;
        float S = RedS[rr*4+0]+RedS[rr*4+1]+RedS[rr*4+2]+RedS[rr*4+3];
        float Q = RedQ[rr*4+0]+RedQ[rr*4+1]+RedQ[rr*4+2]+RedQ[rr*4+3];
        float mean = S*(1.0f/256.0f);
        float var  = Q*(1.0f/256.0f) - mean*mean;
        float rstd = rsqrtf(var + 1e-5f);
        const bf16_t* pr = Pres + (size_t)row*256;
        if (OUTM==3){
          bf16_t* po = (bf16_t*)Cv + (size_t)row*256;
          #pragma unroll
          for (int nt=0; nt<4; nt++){
            float v = acc[mt][nt][r] + bv[nt] + bf2f(pr[wn*64 + nt*16 + l15]);
            po[wn*64 + nt*16 + l15] = f2bf((v-mean)*rstd*gv[nt] + bbv[nt]);
          }
        } else {
          float s2 = 0.f;
          #pragma unroll
          for (int nt=0; nt<4; nt++){
            float v = acc[mt][nt][r] + bv[nt] + bf2f(pr[wn*64 + nt*16 + l15]);
            s2 += ((v-mean)*rstd*gv[nt] + bbv[nt]) * wv[nt];
          }
          s2 += __shfl_xor(s2,1); s2 += __shfl_xor(s2,2);
          s2 += __shfl_xor(s2,4); s2 += __shfl_xor(s2,8);
          s2p[mt][r] = s2;
        }
      }
    if (OUTM==5){
      __syncthreads();
      #pragma unroll
      for (int mt=0; mt<4; mt++)
        #pragma unroll
        for (int r=0; r<4; r++)
          if (l15==0) RedS[(wh*64 + mt*16 + quad*4 + r)*4 + wn] = s2p[mt][r];
      __syncthreads();
      if (w < 2){
        int rr = w*64 + lane;
        float S = RedS[rr*4+0]+RedS[rr*4+1]+RedS[rr*4+2]+RedS[rr*4+3];
        ((float*)Cv)[m0 + rr] = S + obp[0];
      }
    }
  }
}

// ---------------- MFMA attention (r16: remap + exp2 + setprio) ----------------
__global__ __launch_bounds__(256) void k_attn(const bf16_t* __restrict__ Qm,
    const bf16_t* __restrict__ Km, const bf16_t* __restrict__ VT,
    const float* __restrict__ valid, bf16_t* __restrict__ AO)
{
  __shared__ bf16_t Pbuf[4][2][2][16][40];   // [wave][qtile][slot][q][key] 20 KB
  __shared__ float  Smask[512];              // 0 or -1e10*log2e
  int t = threadIdx.x, wave = t>>6, lane = t&63, l15 = lane&15, quad = lane>>4;
  int lid = blockIdx.x + 8*blockIdx.y + 1024*blockIdx.z;    // dispatch order
  int hp = lid & 3, pb = (lid>>2)&1, g = (lid>>3)&7, bh = lid>>6;
  int h  = hp*2 + (g&1);          // head: pair hp, parity from g
  int qc = g>>1;
  int b  = bh*2 + pb;
  int q0 = qc*128;

  Smask[t]     = (valid[b*Ss + t      ] != 0.f) ? 0.f : -1.44269504e10f;
  Smask[t+256] = (valid[b*Ss + t + 256] != 0.f) ? 0.f : -1.44269504e10f;
  __syncthreads();

  short8 aQ0 = ld_bf8(Qm + (size_t)(b*Ss + q0 + (wave*2  )*16 + l15)*256 + h*32 + quad*8);
  short8 aQ1 = ld_bf8(Qm + (size_t)(b*Ss + q0 + (wave*2+1)*16 + l15)*256 + h*32 + quad*8);
  const bf16_t* Kb = Km + (size_t)(b*Ss)*256 + h*32;          // + key*256
  const bf16_t* Vb = VT + ((size_t)b*256 + h*32)*512;         // + d*512 + key

  f32x4 z = {0.f,0.f,0.f,0.f};
  f32x4 O0[2] = {z,z}, O1[2] = {z,z};
  float ls0 = 0.f, ls1 = 0.f;

  auto process = [&](int kt2n, short8 K0, short8 K1){
    int s = kt2n & 1;
    #pragma unroll
    for (int half=0; half<2; half++){
      short8 aK = half ? K1 : K0;
      int ktile = kt2n*2 + half;
      __builtin_amdgcn_s_setprio(1);
      f32x4 s0 = __builtin_amdgcn_mfma_f32_16x16x32_bf16(aK, aQ0, z, 0,0,0);
      f32x4 s1 = __builtin_amdgcn_mfma_f32_16x16x32_bf16(aK, aQ1, z, 0,0,0);
      __builtin_amdgcn_s_setprio(0);
      float4 mb = *(const float4*)&Smask[ktile*16 + quad*4];
      float p00 = exp2_hw(s0[0] + mb.x);    // Q pre-scaled by QS*log2e
      float p01 = exp2_hw(s0[1] + mb.y);
      float p02 = exp2_hw(s0[2] + mb.z);
      float p03 = exp2_hw(s0[3] + mb.w);
      float p10 = exp2_hw(s1[0] + mb.x);
      float p11 = exp2_hw(s1[1] + mb.y);
      float p12 = exp2_hw(s1[2] + mb.z);
      float p13 = exp2_hw(s1[3] + mb.w);
      ls0 += (p00+p01)+(p02+p03);
      ls1 += (p10+p11)+(p12+p13);
      uint2 w0 = { pk_bf16(p00,p01), pk_bf16(p02,p03) };
      uint2 w1 = { pk_bf16(p10,p11), pk_bf16(p12,p13) };
      *(uint2*)&Pbuf[wave][0][s][l15][half*16 + quad*4] = w0;
      *(uint2*)&Pbuf[wave][1][s][l15][half*16 + quad*4] = w1;
    }
  };
  auto loadK = [&](int n, short8& K0, short8& K1){
    K0 = ld_bf8(Kb + (size_t)((n*2  )*16 + l15)*256 + quad*8);
    K1 = ld_bf8(Kb + (size_t)((n*2+1)*16 + l15)*256 + quad*8);
  };
  auto loadV = [&](int n, short8& V0, short8& V1){
    V0 = ld_bf8(Vb + (size_t)(l15   )*512 + n*32 + quad*8);
    V1 = ld_bf8(Vb + (size_t)(16+l15)*512 + n*32 + quad*8);
  };

  short8 cK0, cK1, pK0, pK1, nK0, nK1;
  short8 cV0, cV1, mV0, mV1, nV0, nV1;
  loadK(0, cK0, cK1);
  process(0, cK0, cK1);
  loadK(1, pK0, pK1);
  loadV(0, cV0, cV1);
  loadV(1, mV0, mV1);

  #pragma unroll 2
  for (int kt2=0; kt2<16; kt2++){
    if (kt2+2 < 16){ loadK(kt2+2, nK0, nK1); loadV(kt2+2, nV0, nV1); }
    int s = kt2 & 1;
    short8 aP0 = ld_bf8(&Pbuf[wave][0][s][l15][quad*8]);
    short8 aP1 = ld_bf8(&Pbuf[wave][1][s][l15][quad*8]);
    __builtin_amdgcn_s_setprio(1);
    O0[0] = __builtin_amdgcn_mfma_f32_16x16x32_bf16(aP0, cV0, O0[0], 0,0,0);
    O0[1] = __builtin_amdgcn_mfma_f32_16x16x32_bf16(aP0, cV1, O0[1], 0,0,0);
    O1[0] = __builtin_amdgcn_mfma_f32_16x16x32_bf16(aP1, cV0, O1[0], 0,0,0);
    O1[1] = __builtin_amdgcn_mfma_f32_16x16x32_bf16(aP1, cV1, O1[1], 0,0,0);
    __builtin_amdgcn_s_setprio(0);
    if (kt2+1 < 16) process(kt2+1, pK0, pK1);
    pK0 = nK0; pK1 = nK1;
    cV0 = mV0; cV1 = mV1; mV0 = nV0; mV1 = nV1;
  }

  ls0 += __shfl_xor(ls0,16); ls0 += __shfl_xor(ls0,32);
  ls1 += __shfl_xor(ls1,16); ls1 += __shfl_xor(ls1,32);
  float linv0 = (ls0 > 0.f) ? 1.0f/ls0 : 0.f;
  float linv1 = (ls1 > 0.f) ? 1.0f/ls1 : 0.f;
  float i0[4], i1[4];
  #pragma unroll
  for (int r=0; r<4; r++){
    i0[r] = __shfl(linv0, quad*4 + r);
    i1[r] = __shfl(linv1, quad*4 + r);
  }
  size_t r0 = (size_t)(b*Ss + q0 + (wave*2  )*16);
  size_t r1 = (size_t)(b*Ss + q0 + (wave*2+1)*16);
  #pragma unroll
  for (int nt=0; nt<2; nt++)
    #pragma unroll
    for (int r=0; r<4; r++){
      AO[(r0 + quad*4 + r)*256 + h*32 + nt*16 + l15] = f2bf(O0[nt][r]*i0[r]);
      AO[(r1 + quad*4 + r)*256 + h*32 + nt*16 + l15] = f2bf(O1[nt][r]*i1[r]);
    }
}

// ---------------- final: p = exp(logits)*valid, normalize per batch -----------
__global__ __launch_bounds__(256) void k_final(const float* __restrict__ L,
    const float* __restrict__ valid, float* __restrict__ out)
{
  __shared__ float wsum[4];
  int b = blockIdx.x, t = threadIdx.x;
  float e0 = __expf(L[b*Ss + t      ]) * valid[b*Ss + t      ];
  float e1 = __expf(L[b*Ss + 256 + t]) * valid[b*Ss + 256 + t];
  float s = e0 + e1;
  #pragma unroll
  for (int o=32;o>0;o>>=1) s += __shfl_xor(s,o);
  if ((t&63)==0) wsum[t>>6] = s;
  __syncthreads();
  float tot = wsum[0]+wsum[1]+wsum[2]+wsum[3];
  out[b*Ss + t      ] = e0/tot;
  out[b*Ss + 256 + t] = e1/tot;
}

// ============================================================================
extern "C" void kernel_launch(void* const* d_in, const int* in_sizes, int n_in,
                              void* d_out, int out_size, void* d_ws, size_t ws_size,
                              hipStream_t stream)
{
  #define F(i) ((const float*)d_in[(i)])
  bool sig = (in_sizes[33] == 256);   // signature order vs dict order
  const float* d_eqW  = F(sig?35:33); const float* d_eqb  = F(sig?36:34);
  const float* d_ekW  = F(sig?37:35); const float* d_ekb  = F(sig?38:36);
  const float* d_evW  = F(sig?39:37); const float* d_evb  = F(sig?40:38);
  const float* d_eoW  = F(sig?41:39); const float* d_eob  = F(sig?42:40);
  const float* d_ln1g = F(sig?33:41); const float* d_ln1b = F(sig?34:42);

  // ---- workspace (~163 MiB) ----
  char* w = (char*)d_ws;
  bf16_t* P0 = (bf16_t*)w; w += (size_t)Mm*Hh*2;   // 32 MiB residual (enc)
  bf16_t* P1 = (bf16_t*)w; w += (size_t)Mm*Hh*2;   // 32 MiB residual (dec)
  bf16_t* H0 = (bf16_t*)w; w += (size_t)Mm*Hh*2;   // 32 MiB Q / AO / gelu
  bf16_t* H1 = (bf16_t*)w;                          // 32 MiB K / xs alias
  bf16_t* xs = (bf16_t*)w; w += (size_t)Mm*Hh*2;
  bf16_t* H2 = (bf16_t*)w;                          // 32 MiB VT / xt alias
  bf16_t* xt = (bf16_t*)w; w += (size_t)Mm*Hh*2;
  bf16_t* Wa = (bf16_t*)w; w += (size_t)(2*16384 + 16*65536)*2;  // 2.1 MiB
  float*  valid  = (float*)w; w += (size_t)Mm*4;
  float*  logits = (float*)w; w += (size_t)Mm*4;
  float* out = (float*)d_out;

  unsigned o_sem = 0, o_tem = 16384;
  unsigned o_w[16]; for (int i=0;i<16;i++) o_w[i] = 32768 + i*65536u;
  Prep18 pp;
  const float* srcs[18] = { F(5), F(7), F(9), F(11), F(13), F(15), F(19), F(21),
                            F(25), F(27), F(29), F(31), d_eqW, d_ekW, d_evW, d_eoW,
                            F(45), F(47) };
  unsigned offs[18] = { o_sem, o_tem, o_w[0],o_w[1],o_w[2],o_w[3],o_w[4],o_w[5],
                        o_w[6],o_w[7],o_w[8],o_w[9],o_w[10],o_w[11],o_w[12],o_w[13],
                        o_w[14],o_w[15] };
  for (int i=0;i<18;i++){ pp.d[i].s = srcs[i]; pp.d[i].off = offs[i]; pp.d[i].K = (i<2)?64:256; }

  dim3 blk(256);
  dim3 blk512(512);
  dim3 gLN(Mm/4);
  dim3 gG(Mm/64);
  dim3 gG2(Mm/128);
  dim3 gA(NHh, Bb, 4);
  dim3 gP(256, 18);
  const float* NF = nullptr; const bf16_t* NB = nullptr;
  // 1/sqrt(32) * log2(e) folded into Q so attention uses native exp2
  const float QS = 0.17677669529663687f * 1.4426950408889634f;

  k_prep<<<gP, blk, 0, stream>>>(pp, Wa);
  k_ln0<<<gLN, blk, 0, stream>>>(F(0), F(1),F(2), F(3),F(4), xs, xt, valid);

  // emb pair (independent, K=64)
  {
    GemmJobs js;
    js.j[0] = { xs, Wa+o_sem, F(6), P0, 0, 1.0f };
    js.j[1] = { xt, Wa+o_tem, F(8), P1, 0, 1.0f };
    js.j[2] = js.j[0];
    k_gemm3<64><<<dim3(Mm/128,2), blk512, 0, stream>>>(js);
  }

  auto QJ = [&](const bf16_t* A, int wq, int wk, int wv,
                const float* bq, const float* bk, const float* bv2,
                const bf16_t* Ak){
    QkvJob j; j.A = A;
    j.Wt0 = Wa+o_w[wq]; j.Wt1 = Wa+o_w[wk]; j.Wt2 = Wa+o_w[wv];
    j.b0 = bq; j.b1 = bk; j.b2 = bv2;
    j.C0 = H0; j.C1 = H1; j.C2 = H2; j.qs = QS;
    (void)Ak; return j;
  };

  // ---- encoder ----
  {
    QkvJob j = QJ(P0, 0,1,2, F(10),F(12),F(14), P0);
    k_qkv<<<gG, blk, 0, stream>>>(j);
  }
  k_attn<<<gA, blk, 0, stream>>>(H0, H1, H2, valid, H0);
  k_gemm<0,3,256><<<gG2, blk512, 0, stream>>>(H0, Wa+o_w[3], F(16), P0, P0, F(17),F(18), NF,NF);
  k_gemm<1,0,256><<<gG2, blk512, 0, stream>>>(P0, Wa+o_w[4], F(20), H0, NB,NF,NF,NF,NF);
  k_gemm<0,3,256><<<gG2, blk512, 0, stream>>>(H0, Wa+o_w[5], F(22), P0, P0, F(23),F(24), NF,NF);

  // ---- decoder self-attention ----
  {
    QkvJob j = QJ(P1, 6,7,8, F(26),F(28),F(30), P1);
    k_qkv<<<gG, blk, 0, stream>>>(j);
  }
  k_attn<<<gA, blk, 0, stream>>>(H0, H1, H2, valid, H0);
  k_gemm<0,3,256><<<gG2, blk512, 0, stream>>>(H0, Wa+o_w[9], F(32), P1, P1, d_ln1g,d_ln1b, NF,NF);

  // ---- decoder cross-attention: Q from P1, K/V from P0 ----
  {
    k_gemm<0,0,256><<<gG2, blk512, 0, stream>>>(P1, Wa+o_w[10], d_eqb, H0, NB,NF,NF,NF,NF);
    GemmJobs js;
    js.j[0] = { P0, Wa+o_w[11], d_ekb, H1, 0, 1.0f };
    js.j[1] = { P0, Wa+o_w[12], d_evb, H2, 2, 1.0f };
    js.j[2] = js.j[0];
    k_gemm3<256><<<dim3(Mm/128,2), blk512, 0, stream>>>(js);
  }
  k_attn<<<gA, blk, 0, stream>>>(H0, H1, H2, valid, H0);
  k_gemm<0,3,256><<<gG2, blk512, 0, stream>>>(H0, Wa+o_w[13], d_eob, P1, P1, F(43),F(44), NF,NF);

  // ---- decoder FFN + fused ln3 + logits ----
  k_gemm<1,0,256><<<gG2, blk512, 0, stream>>>(P1, Wa+o_w[14], F(46), H0, NB,NF,NF,NF,NF);
  k_gemm<0,5,256><<<gG2, blk512, 0, stream>>>(H0, Wa+o_w[15], F(48), logits, P1, F(49),F(50), F(51),F(52));

  k_final<<<dim3(Bb), blk, 0, stream>>>(logits, valid, out);
  #undef F
}

// Round 5
// 1126.525 us; speedup vs baseline: 1.6399x; 1.6399x over previous
//
#include <hip/hip_runtime.h>
#include <hip/hip_bf16.h>

// ============================================================================
// TransformerChoiceNet forward. Round 19: GEMM family back to r2 geometry
// (64x256 tile, 256 thr, 4 waves) but with 2-phase double-buffered LDS:
// stage(k+1) issued BEFORE compute(k), single barrier per K-step whose
// vmcnt(0) drain is covered by the MFMA phase. LDS 80KB -> 2 blocks/CU.
// k_qkv / k_attn / rest byte-identical to r16 (1019us baseline).
// B=128 S=512 D=64 H=256 NH=8 HD=32, M=B*S=65536.
// ============================================================================

#define Bb  128
#define Ss  512
#define Hh  256
#define NHh 8
#define Mm  (Bb*Ss)

typedef unsigned short bf16_t;
typedef __attribute__((ext_vector_type(8))) short short8;
typedef __attribute__((ext_vector_type(4))) float f32x4;

__device__ __forceinline__ float bf2f(bf16_t h){
  union { unsigned int u; float f; } v; v.u = ((unsigned int)h)<<16; return v.f;
}
__device__ __forceinline__ bf16_t f2bf(float f){
  union { float f; unsigned int u; } v; v.f = f;
  unsigned int r = (v.u + 0x7fffu + ((v.u>>16)&1u)) >> 16;   // RNE
  return (bf16_t)r;
}
__device__ __forceinline__ unsigned pk_bf16(float a, float b){  // packed RNE cvt
  union { __hip_bfloat162 h; unsigned u; } v;
  v.h = __float22bfloat162_rn(float2{a,b});
  return v.u;
}
__device__ __forceinline__ short8 ld_bf8(const bf16_t* p){   // 16B load
  union { uint4 u; short8 s; } v; v.u = *(const uint4*)p; return v.s;
}
__device__ __forceinline__ void gload16(const bf16_t* g, bf16_t* l){
  __builtin_amdgcn_global_load_lds(
      (const __attribute__((address_space(1))) void*)g,
      (__attribute__((address_space(3))) void*)l, 16, 0, 0);
}
__device__ __forceinline__ float exp2_hw(float x){           // native 2^x
  float r; asm("v_exp_f32 %0, %1" : "=v"(r) : "v"(x)); return r;
}
__device__ __forceinline__ float gelu_f(float x){
  // NewGELU; tanh via native exp + rcp: tanh(u) = 1 - 2/(e^{2u}+1)
  float u = 0.7978845608028654f*(x + 0.044715f*x*x*x);
  float e = __expf(2.0f*u);
  float th = 1.0f - 2.0f*__builtin_amdgcn_rcpf(e + 1.0f);
  return 0.5f*x*(1.0f + th);
}

// ---------------- weight prep: fp32 W[k][n] -> bf16 Wt[n][k] ------------------
struct PrepDesc { const float* s; unsigned off; int K; };
struct Prep18  { PrepDesc d[18]; };

__global__ __launch_bounds__(256) void k_prep(Prep18 p, bf16_t* __restrict__ arena)
{
  PrepDesc dd = p.d[blockIdx.y];
  int i = blockIdx.x*256 + threadIdx.x;
  if (i < dd.K*256){
    int k = i>>8, n = i&255;
    arena[dd.off + n*dd.K + k] = f2bf(dd.s[i]);
  }
}

// ---------------- LN0 (two gains) + valid mask; bf16 out ----------------------
__global__ __launch_bounds__(256) void k_ln0(const float* __restrict__ src,
    const float* __restrict__ gs, const float* __restrict__ bs,
    const float* __restrict__ gt, const float* __restrict__ bt,
    bf16_t* __restrict__ xs, bf16_t* __restrict__ xt, float* __restrict__ valid)
{
  int row  = blockIdx.x*4 + (threadIdx.x>>6);
  int lane = threadIdx.x & 63;
  float x = src[(size_t)row*64 + lane];
  float s = x;
  #pragma unroll
  for (int o=32;o>0;o>>=1) s += __shfl_xor(s,o);
  float mean = s*(1.0f/64.0f);
  float d = x - mean;
  float ss = d*d;
  #pragma unroll
  for (int o=32;o>0;o>>=1) ss += __shfl_xor(ss,o);
  float r = rsqrtf(ss*(1.0f/64.0f) + 1e-5f);
  float xn = d*r;
  xs[(size_t)row*64+lane] = f2bf(xn*gs[lane] + bs[lane]);
  xt[(size_t)row*64+lane] = f2bf(xn*gt[lane] + bt[lane]);
  if (lane==0) valid[row] = (s != 0.0f) ? 1.0f : 0.0f;
}

// ---------------- merged independent GEMMs (2-phase dbuf) ---------------------
struct GemmJob  { const bf16_t* A; const bf16_t* Wt; const float* bias; bf16_t* C;
                  int outm; float cs; };
struct GemmJobs { GemmJob j[3]; };

template<int KK>
__global__ __launch_bounds__(256,2) void k_gemm3(GemmJobs jobs)
{
  __shared__ bf16_t As[2][8*512];    // 16 KB
  __shared__ bf16_t Bs[2][32*512];   // 64 KB
  GemmJob jb = jobs.j[blockIdx.y];
  int t = threadIdx.x, w = t>>6, lane = t&63, l15 = lane&15, quad = lane>>4;
  int m0 = blockIdx.x*64;
  f32x4 z = {0.f,0.f,0.f,0.f};
  f32x4 acc[4][4] = {{z,z,z,z},{z,z,z,z},{z,z,z,z},{z,z,z,z}};
  constexpr int NT = KK/64;

  auto stage = [&](int ki, int buf){
    #pragma unroll
    for (int j=0; j<2; j++){
      int id = 2*w + j; int kc32 = id>>2, mt = id&3;
      gload16(jb.A + (size_t)(m0 + mt*16 + l15)*KK + ki*64 + kc32*32 + quad*8,
              &As[buf][id*512]);
    }
    #pragma unroll
    for (int j=0; j<8; j++){
      int id = 8*w + j; int kc32 = id>>4, gnt = id&15;
      gload16(jb.Wt + (size_t)(gnt*16 + l15)*KK + ki*64 + kc32*32 + quad*8,
              &Bs[buf][id*512]);
    }
  };

  stage(0, 0);
  __syncthreads();
  #pragma unroll
  for (int ki=0; ki<NT; ki++){
    int cur = ki & 1;
    if (ki+1 < NT) stage(ki+1, cur^1);     // prefetch flies under MFMA phase
    #pragma unroll
    for (int kc=0; kc<2; kc++){
      short8 a[4], b[4];
      #pragma unroll
      for (int mt=0; mt<4; mt++) a[mt] = ld_bf8(&As[cur][(kc*4+mt)*512 + lane*8]);
      #pragma unroll
      for (int nt=0; nt<4; nt++) b[nt] = ld_bf8(&Bs[cur][(kc*16 + w*4 + nt)*512 + lane*8]);
      #pragma unroll
      for (int mt=0; mt<4; mt++)
        #pragma unroll
        for (int nt=0; nt<4; nt++)
          acc[mt][nt] = __builtin_amdgcn_mfma_f32_16x16x32_bf16(a[mt], b[nt], acc[mt][nt], 0,0,0);
    }
    __syncthreads();                       // drains prefetch + syncs buffers
  }

  float bv[4];
  #pragma unroll
  for (int nt=0; nt<4; nt++) bv[nt] = jb.bias[w*64 + nt*16 + l15];
  float cs = jb.cs;

  if (jb.outm == 0){
    #pragma unroll
    for (int mt=0; mt<4; mt++)
      #pragma unroll
      for (int nt=0; nt<4; nt++){
        int m = m0 + mt*16 + quad*4;
        int col = w*64 + nt*16 + l15;
        #pragma unroll
        for (int r=0; r<4; r++)
          jb.C[(size_t)(m+r)*256 + col] = f2bf((acc[mt][nt][r] + bv[nt])*cs);
      }
  } else {
    #pragma unroll
    for (int mt=0; mt<4; mt++)
      #pragma unroll
      for (int nt=0; nt<4; nt++){
        int m = m0 + mt*16 + quad*4;
        int col = w*64 + nt*16 + l15;
        uint2 pk = { pk_bf16(acc[mt][nt][0]+bv[nt], acc[mt][nt][1]+bv[nt]),
                     pk_bf16(acc[mt][nt][2]+bv[nt], acc[mt][nt][3]+bv[nt]) };
        *(uint2*)&jb.C[((size_t)((m>>9)*256 + col))*512 + (m&511)] = pk;
      }
  }
}

// ---------------- fused QKV trio: A staged once, 3 weight loops ---------------
struct QkvJob { const bf16_t* A;
                const bf16_t* Wt0; const bf16_t* Wt1; const bf16_t* Wt2;
                const float* b0; const float* b1; const float* b2;
                bf16_t* C0; bf16_t* C1; bf16_t* C2; float qs; };

__global__ __launch_bounds__(256,2) void k_qkv(QkvJob jb)
{
  __shared__ bf16_t As[32*512];   // 32 KB: full A tile, id = kc32*4 + mt
  __shared__ bf16_t Bs[32*512];   // 32 KB: BK=64 weight tile, id = kc*16 + gnt
  int t = threadIdx.x, w = t>>6, lane = t&63, l15 = lane&15, quad = lane>>4;
  int m0 = blockIdx.x*64;
  f32x4 z = {0.f,0.f,0.f,0.f};

  #pragma unroll
  for (int j=0; j<8; j++){                    // stage FULL A once (8 per wave)
    int id = 8*w + j; int kc32 = id>>2, mt = id&3;
    gload16(jb.A + (size_t)(m0 + mt*16 + l15)*256 + kc32*32 + quad*8,
            &As[id*512]);
  }

  const bf16_t* Wts[3]  = { jb.Wt0, jb.Wt1, jb.Wt2 };
  const float*  bias[3] = { jb.b0,  jb.b1,  jb.b2  };
  bf16_t*       Cs[3]   = { jb.C0,  jb.C1,  jb.C2  };

  #pragma unroll 1
  for (int o=0; o<3; o++){
    const bf16_t* Wt = Wts[o];
    f32x4 acc[4][4] = {{z,z,z,z},{z,z,z,z},{z,z,z,z},{z,z,z,z}};
    #pragma unroll 1
    for (int ki=0; ki<4; ki++){
      #pragma unroll
      for (int j=0; j<8; j++){
        int id = 8*w + j; int kc32 = id>>4, gnt = id&15;
        gload16(Wt + (size_t)(gnt*16 + l15)*256 + ki*64 + kc32*32 + quad*8,
                &Bs[id*512]);
      }
      __syncthreads();                        // drains A stage too (first iter)
      #pragma unroll
      for (int kc=0; kc<2; kc++){
        short8 a[4], b[4];
        #pragma unroll
        for (int mt=0; mt<4; mt++)
          a[mt] = ld_bf8(&As[((ki*2+kc)*4 + mt)*512 + lane*8]);
        #pragma unroll
        for (int nt=0; nt<4; nt++)
          b[nt] = ld_bf8(&Bs[(kc*16 + w*4 + nt)*512 + lane*8]);
        #pragma unroll
        for (int mt=0; mt<4; mt++)
          #pragma unroll
          for (int nt=0; nt<4; nt++)
            acc[mt][nt] = __builtin_amdgcn_mfma_f32_16x16x32_bf16(a[mt], b[nt], acc[mt][nt], 0,0,0);
      }
      __syncthreads();                        // Bs reused next ki / next output
    }
    float bv[4];
    #pragma unroll
    for (int nt=0; nt<4; nt++) bv[nt] = bias[o][w*64 + nt*16 + l15];
    bf16_t* C = Cs[o];
    if (o < 2){                               // Q (scaled) / K: bf16 [M,256]
      float cs = (o==0) ? jb.qs : 1.0f;
      #pragma unroll
      for (int mt=0; mt<4; mt++)
        #pragma unroll
        for (int nt=0; nt<4; nt++){
          int m = m0 + mt*16 + quad*4;
          int col = w*64 + nt*16 + l15;
          #pragma unroll
          for (int r=0; r<4; r++)
            C[(size_t)(m+r)*256 + col] = f2bf((acc[mt][nt][r] + bv[nt])*cs);
        }
    } else {                                  // V -> VT[b][n][s] packed 8B
      #pragma unroll
      for (int mt=0; mt<4; mt++)
        #pragma unroll
        for (int nt=0; nt<4; nt++){
          int m = m0 + mt*16 + quad*4;
          int col = w*64 + nt*16 + l15;
          uint2 pk = { pk_bf16(acc[mt][nt][0]+bv[nt], acc[mt][nt][1]+bv[nt]),
                       pk_bf16(acc[mt][nt][2]+bv[nt], acc[mt][nt][3]+bv[nt]) };
          *(uint2*)&C[((size_t)((m>>9)*256 + col))*512 + (m&511)] = pk;
        }
    }
  }
}

// ---------------- MFMA GEMM (2-phase dbuf) with fused epilogues ---------------
// OUTM: 0 bf16 C[M,256] (EPI 0/1) | 3 LN(Pres+(acc+b)) -> bf16 P |
//       5 like 3 but dot outW -> fp32 logits.
template<int EPI, int OUTM, int KK>
__global__ __launch_bounds__(256,2) void k_gemm(const bf16_t* __restrict__ A,
    const bf16_t* __restrict__ Wt, const float* __restrict__ bias,
    void* __restrict__ Cv, const bf16_t* __restrict__ Pres,
    const float* __restrict__ g, const float* __restrict__ bb,
    const float* __restrict__ oW, const float* __restrict__ obp)
{
  __shared__ bf16_t As[2][8*512];    // 16 KB
  __shared__ bf16_t Bs[2][32*512];   // 64 KB
  int t = threadIdx.x, w = t>>6, lane = t&63, l15 = lane&15, quad = lane>>4;
  int m0 = blockIdx.x*64;
  f32x4 z = {0.f,0.f,0.f,0.f};
  f32x4 acc[4][4] = {{z,z,z,z},{z,z,z,z},{z,z,z,z},{z,z,z,z}};
  constexpr int NT = KK/64;

  auto stage = [&](int ki, int buf){
    #pragma unroll
    for (int j=0; j<2; j++){
      int id = 2*w + j; int kc32 = id>>2, mt = id&3;
      gload16(A + (size_t)(m0 + mt*16 + l15)*KK + ki*64 + kc32*32 + quad*8,
              &As[buf][id*512]);
    }
    #pragma unroll
    for (int j=0; j<8; j++){
      int id = 8*w + j; int kc32 = id>>4, gnt = id&15;
      gload16(Wt + (size_t)(gnt*16 + l15)*KK + ki*64 + kc32*32 + quad*8,
              &Bs[buf][id*512]);
    }
  };

  stage(0, 0);
  __syncthreads();
  #pragma unroll
  for (int ki=0; ki<NT; ki++){
    int cur = ki & 1;
    if (ki+1 < NT) stage(ki+1, cur^1);     // prefetch flies under MFMA phase
    #pragma unroll
    for (int kc=0; kc<2; kc++){
      short8 a[4], b[4];
      #pragma unroll
      for (int mt=0; mt<4; mt++) a[mt] = ld_bf8(&As[cur][(kc*4+mt)*512 + lane*8]);
      #pragma unroll
      for (int nt=0; nt<4; nt++) b[nt] = ld_bf8(&Bs[cur][(kc*16 + w*4 + nt)*512 + lane*8]);
      #pragma unroll
      for (int mt=0; mt<4; mt++)
        #pragma unroll
        for (int nt=0; nt<4; nt++)
          acc[mt][nt] = __builtin_amdgcn_mfma_f32_16x16x32_bf16(a[mt], b[nt], acc[mt][nt], 0,0,0);
    }
    __syncthreads();                       // drains prefetch + syncs buffers
  }

  float bv[4];
  #pragma unroll
  for (int nt=0; nt<4; nt++) bv[nt] = bias[w*64 + nt*16 + l15];

  if (OUTM==0){
    #pragma unroll
    for (int mt=0; mt<4; mt++)
      #pragma unroll
      for (int nt=0; nt<4; nt++)
        #pragma unroll
        for (int r=0; r<4; r++){
          int row = m0 + mt*16 + quad*4 + r;
          int col = w*64 + nt*16 + l15;
          float v = acc[mt][nt][r] + bv[nt];
          if (EPI==1) v = gelu_f(v);
          ((bf16_t*)Cv)[(size_t)row*256 + col] = f2bf(v);
        }
  } else {
    float* RedS = (float*)As;          // [64][4]
    float* RedQ = RedS + 256;          // [64][4]
    #pragma unroll
    for (int mt=0; mt<4; mt++)
      #pragma unroll
      for (int r=0; r<4; r++){
        int row = m0 + mt*16 + quad*4 + r;
        const bf16_t* pr = Pres + (size_t)row*256;
        float s = 0.f, q = 0.f;
        #pragma unroll
        for (int nt=0; nt<4; nt++){
          float v = acc[mt][nt][r] + bv[nt] + bf2f(pr[w*64 + nt*16 + l15]);
          s += v; q += v*v;
        }
        s += __shfl_xor(s,1); s += __shfl_xor(s,2);
        s += __shfl_xor(s,4); s += __shfl_xor(s,8);
        q += __shfl_xor(q,1); q += __shfl_xor(q,2);
        q += __shfl_xor(q,4); q += __shfl_xor(q,8);
        if (l15==0){
          int rr = mt*16 + quad*4 + r;
          RedS[rr*4 + w] = s; RedQ[rr*4 + w] = q;
        }
      }
    __syncthreads();

    float gv[4], bbv[4], wv[4];
    #pragma unroll
    for (int nt=0; nt<4; nt++){ gv[nt] = g[w*64+nt*16+l15]; bbv[nt] = bb[w*64+nt*16+l15]; }
    if (OUTM==5)
      #pragma unroll
      for (int nt=0; nt<4; nt++) wv[nt] = oW[w*64+nt*16+l15];

    float s2p[4][4];
    #pragma unroll
    for (int mt=0; mt<4; mt++)
      #pragma unroll
      for (int r=0; r<4; r++){
        int rr = mt*16 + quad*4 + r;
        int row = m0 + rr;
        float S = RedS[rr*4+0]+RedS[rr*4+1]+RedS[rr*4+2]+RedS[rr*4+3];
        float Q = RedQ[rr*4+0]+RedQ[rr*4+1]+RedQ[rr*4+2]+RedQ[rr*4+3];
        float mean = S*(1.0f/256.0f);
        float var  = Q*(1.0f/256.0f) - mean*mean;
        float rstd = rsqrtf(var + 1e-5f);
        const bf16_t* pr = Pres + (size_t)row*256;
        if (OUTM==3){
          bf16_t* po = (bf16_t*)Cv + (size_t)row*256;
          #pragma unroll
          for (int nt=0; nt<4; nt++){
            float v = acc[mt][nt][r] + bv[nt] + bf2f(pr[w*64 + nt*16 + l15]);
            po[w*64 + nt*16 + l15] = f2bf((v-mean)*rstd*gv[nt] + bbv[nt]);
          }
        } else {
          float s2 = 0.f;
          #pragma unroll
          for (int nt=0; nt<4; nt++){
            float v = acc[mt][nt][r] + bv[nt] + bf2f(pr[w*64 + nt*16 + l15]);
            s2 += ((v-mean)*rstd*gv[nt] + bbv[nt]) * wv[nt];
          }
          s2 += __shfl_xor(s2,1); s2 += __shfl_xor(s2,2);
          s2 += __shfl_xor(s2,4); s2 += __shfl_xor(s2,8);
          s2p[mt][r] = s2;
        }
      }
    if (OUTM==5){
      __syncthreads();
      #pragma unroll
      for (int mt=0; mt<4; mt++)
        #pragma unroll
        for (int r=0; r<4; r++)
          if (l15==0) RedS[(mt*16 + quad*4 + r)*4 + w] = s2p[mt][r];
      __syncthreads();
      if (w==0){
        float S = RedS[lane*4+0]+RedS[lane*4+1]+RedS[lane*4+2]+RedS[lane*4+3];
        ((float*)Cv)[m0 + lane] = S + obp[0];
      }
    }
  }
}

// ---------------- MFMA attention (r16: remap + exp2 + setprio) ----------------
__global__ __launch_bounds__(256) void k_attn(const bf16_t* __restrict__ Qm,
    const bf16_t* __restrict__ Km, const bf16_t* __restrict__ VT,
    const float* __restrict__ valid, bf16_t* __restrict__ AO)
{
  __shared__ bf16_t Pbuf[4][2][2][16][40];   // [wave][qtile][slot][q][key] 20 KB
  __shared__ float  Smask[512];              // 0 or -1e10*log2e
  int t = threadIdx.x, wave = t>>6, lane = t&63, l15 = lane&15, quad = lane>>4;
  int lid = blockIdx.x + 8*blockIdx.y + 1024*blockIdx.z;    // dispatch order
  int hp = lid & 3, pb = (lid>>2)&1, g = (lid>>3)&7, bh = lid>>6;
  int h  = hp*2 + (g&1);          // head: pair hp, parity from g
  int qc = g>>1;
  int b  = bh*2 + pb;
  int q0 = qc*128;

  Smask[t]     = (valid[b*Ss + t      ] != 0.f) ? 0.f : -1.44269504e10f;
  Smask[t+256] = (valid[b*Ss + t + 256] != 0.f) ? 0.f : -1.44269504e10f;
  __syncthreads();

  short8 aQ0 = ld_bf8(Qm + (size_t)(b*Ss + q0 + (wave*2  )*16 + l15)*256 + h*32 + quad*8);
  short8 aQ1 = ld_bf8(Qm + (size_t)(b*Ss + q0 + (wave*2+1)*16 + l15)*256 + h*32 + quad*8);
  const bf16_t* Kb = Km + (size_t)(b*Ss)*256 + h*32;          // + key*256
  const bf16_t* Vb = VT + ((size_t)b*256 + h*32)*512;         // + d*512 + key

  f32x4 z = {0.f,0.f,0.f,0.f};
  f32x4 O0[2] = {z,z}, O1[2] = {z,z};
  float ls0 = 0.f, ls1 = 0.f;

  auto process = [&](int kt2n, short8 K0, short8 K1){
    int s = kt2n & 1;
    #pragma unroll
    for (int half=0; half<2; half++){
      short8 aK = half ? K1 : K0;
      int ktile = kt2n*2 + half;
      __builtin_amdgcn_s_setprio(1);
      f32x4 s0 = __builtin_amdgcn_mfma_f32_16x16x32_bf16(aK, aQ0, z, 0,0,0);
      f32x4 s1 = __builtin_amdgcn_mfma_f32_16x16x32_bf16(aK, aQ1, z, 0,0,0);
      __builtin_amdgcn_s_setprio(0);
      float4 mb = *(const float4*)&Smask[ktile*16 + quad*4];
      float p00 = exp2_hw(s0[0] + mb.x);    // Q pre-scaled by QS*log2e
      float p01 = exp2_hw(s0[1] + mb.y);
      float p02 = exp2_hw(s0[2] + mb.z);
      float p03 = exp2_hw(s0[3] + mb.w);
      float p10 = exp2_hw(s1[0] + mb.x);
      float p11 = exp2_hw(s1[1] + mb.y);
      float p12 = exp2_hw(s1[2] + mb.z);
      float p13 = exp2_hw(s1[3] + mb.w);
      ls0 += (p00+p01)+(p02+p03);
      ls1 += (p10+p11)+(p12+p13);
      uint2 w0 = { pk_bf16(p00,p01), pk_bf16(p02,p03) };
      uint2 w1 = { pk_bf16(p10,p11), pk_bf16(p12,p13) };
      *(uint2*)&Pbuf[wave][0][s][l15][half*16 + quad*4] = w0;
      *(uint2*)&Pbuf[wave][1][s][l15][half*16 + quad*4] = w1;
    }
  };
  auto loadK = [&](int n, short8& K0, short8& K1){
    K0 = ld_bf8(Kb + (size_t)((n*2  )*16 + l15)*256 + quad*8);
    K1 = ld_bf8(Kb + (size_t)((n*2+1)*16 + l15)*256 + quad*8);
  };
  auto loadV = [&](int n, short8& V0, short8& V1){
    V0 = ld_bf8(Vb + (size_t)(l15   )*512 + n*32 + quad*8);
    V1 = ld_bf8(Vb + (size_t)(16+l15)*512 + n*32 + quad*8);
  };

  short8 cK0, cK1, pK0, pK1, nK0, nK1;
  short8 cV0, cV1, mV0, mV1, nV0, nV1;
  loadK(0, cK0, cK1);
  process(0, cK0, cK1);
  loadK(1, pK0, pK1);
  loadV(0, cV0, cV1);
  loadV(1, mV0, mV1);

  #pragma unroll 2
  for (int kt2=0; kt2<16; kt2++){
    if (kt2+2 < 16){ loadK(kt2+2, nK0, nK1); loadV(kt2+2, nV0, nV1); }
    int s = kt2 & 1;
    short8 aP0 = ld_bf8(&Pbuf[wave][0][s][l15][quad*8]);
    short8 aP1 = ld_bf8(&Pbuf[wave][1][s][l15][quad*8]);
    __builtin_amdgcn_s_setprio(1);
    O0[0] = __builtin_amdgcn_mfma_f32_16x16x32_bf16(aP0, cV0, O0[0], 0,0,0);
    O0[1] = __builtin_amdgcn_mfma_f32_16x16x32_bf16(aP0, cV1, O0[1], 0,0,0);
    O1[0] = __builtin_amdgcn_mfma_f32_16x16x32_bf16(aP1, cV0, O1[0], 0,0,0);
    O1[1] = __builtin_amdgcn_mfma_f32_16x16x32_bf16(aP1, cV1, O1[1], 0,0,0);
    __builtin_amdgcn_s_setprio(0);
    if (kt2+1 < 16) process(kt2+1, pK0, pK1);
    pK0 = nK0; pK1 = nK1;
    cV0 = mV0; cV1 = mV1; mV0 = nV0; mV1 = nV1;
  }

  ls0 += __shfl_xor(ls0,16); ls0 += __shfl_xor(ls0,32);
  ls1 += __shfl_xor(ls1,16); ls1 += __shfl_xor(ls1,32);
  float linv0 = (ls0 > 0.f) ? 1.0f/ls0 : 0.f;
  float linv1 = (ls1 > 0.f) ? 1.0f/ls1 : 0.f;
  float i0[4], i1[4];
  #pragma unroll
  for (int r=0; r<4; r++){
    i0[r] = __shfl(linv0, quad*4 + r);
    i1[r] = __shfl(linv1, quad*4 + r);
  }
  size_t r0 = (size_t)(b*Ss + q0 + (wave*2  )*16);
  size_t r1 = (size_t)(b*Ss + q0 + (wave*2+1)*16);
  #pragma unroll
  for (int nt=0; nt<2; nt++)
    #pragma unroll
    for (int r=0; r<4; r++){
      AO[(r0 + quad*4 + r)*256 + h*32 + nt*16 + l15] = f2bf(O0[nt][r]*i0[r]);
      AO[(r1 + quad*4 + r)*256 + h*32 + nt*16 + l15] = f2bf(O1[nt][r]*i1[r]);
    }
}

// ---------------- final: p = exp(logits)*valid, normalize per batch -----------
__global__ __launch_bounds__(256) void k_final(const float* __restrict__ L,
    const float* __restrict__ valid, float* __restrict__ out)
{
  __shared__ float wsum[4];
  int b = blockIdx.x, t = threadIdx.x;
  float e0 = __expf(L[b*Ss + t      ]) * valid[b*Ss + t      ];
  float e1 = __expf(L[b*Ss + 256 + t]) * valid[b*Ss + 256 + t];
  float s = e0 + e1;
  #pragma unroll
  for (int o=32;o>0;o>>=1) s += __shfl_xor(s,o);
  if ((t&63)==0) wsum[t>>6] = s;
  __syncthreads();
  float tot = wsum[0]+wsum[1]+wsum[2]+wsum[3];
  out[b*Ss + t      ] = e0/tot;
  out[b*Ss + 256 + t] = e1/tot;
}

// ============================================================================
extern "C" void kernel_launch(void* const* d_in, const int* in_sizes, int n_in,
                              void* d_out, int out_size, void* d_ws, size_t ws_size,
                              hipStream_t stream)
{
  #define F(i) ((const float*)d_in[(i)])
  bool sig = (in_sizes[33] == 256);   // signature order vs dict order
  const float* d_eqW  = F(sig?35:33); const float* d_eqb  = F(sig?36:34);
  const float* d_ekW  = F(sig?37:35); const float* d_ekb  = F(sig?38:36);
  const float* d_evW  = F(sig?39:37); const float* d_evb  = F(sig?40:38);
  const float* d_eoW  = F(sig?41:39); const float* d_eob  = F(sig?42:40);
  const float* d_ln1g = F(sig?33:41); const float* d_ln1b = F(sig?34:42);

  // ---- workspace (~163 MiB) ----
  char* w = (char*)d_ws;
  bf16_t* P0 = (bf16_t*)w; w += (size_t)Mm*Hh*2;   // 32 MiB residual (enc)
  bf16_t* P1 = (bf16_t*)w; w += (size_t)Mm*Hh*2;   // 32 MiB residual (dec)
  bf16_t* H0 = (bf16_t*)w; w += (size_t)Mm*Hh*2;   // 32 MiB Q / AO / gelu
  bf16_t* H1 = (bf16_t*)w;                          // 32 MiB K / xs alias
  bf16_t* xs = (bf16_t*)w; w += (size_t)Mm*Hh*2;
  bf16_t* H2 = (bf16_t*)w;                          // 32 MiB VT / xt alias
  bf16_t* xt = (bf16_t*)w; w += (size_t)Mm*Hh*2;
  bf16_t* Wa = (bf16_t*)w; w += (size_t)(2*16384 + 16*65536)*2;  // 2.1 MiB
  float*  valid  = (float*)w; w += (size_t)Mm*4;
  float*  logits = (float*)w; w += (size_t)Mm*4;
  float* out = (float*)d_out;

  unsigned o_sem = 0, o_tem = 16384;
  unsigned o_w[16]; for (int i=0;i<16;i++) o_w[i] = 32768 + i*65536u;
  Prep18 pp;
  const float* srcs[18] = { F(5), F(7), F(9), F(11), F(13), F(15), F(19), F(21),
                            F(25), F(27), F(29), F(31), d_eqW, d_ekW, d_evW, d_eoW,
                            F(45), F(47) };
  unsigned offs[18] = { o_sem, o_tem, o_w[0],o_w[1],o_w[2],o_w[3],o_w[4],o_w[5],
                        o_w[6],o_w[7],o_w[8],o_w[9],o_w[10],o_w[11],o_w[12],o_w[13],
                        o_w[14],o_w[15] };
  for (int i=0;i<18;i++){ pp.d[i].s = srcs[i]; pp.d[i].off = offs[i]; pp.d[i].K = (i<2)?64:256; }

  dim3 blk(256);
  dim3 gLN(Mm/4);
  dim3 gG(Mm/64);
  dim3 gA(NHh, Bb, 4);
  dim3 gP(256, 18);
  const float* NF = nullptr; const bf16_t* NB = nullptr;
  // 1/sqrt(32) * log2(e) folded into Q so attention uses native exp2
  const float QS = 0.17677669529663687f * 1.4426950408889634f;

  k_prep<<<gP, blk, 0, stream>>>(pp, Wa);
  k_ln0<<<gLN, blk, 0, stream>>>(F(0), F(1),F(2), F(3),F(4), xs, xt, valid);

  // emb pair (independent, K=64)
  {
    GemmJobs js;
    js.j[0] = { xs, Wa+o_sem, F(6), P0, 0, 1.0f };
    js.j[1] = { xt, Wa+o_tem, F(8), P1, 0, 1.0f };
    js.j[2] = js.j[0];
    k_gemm3<64><<<dim3(Mm/64,2), blk, 0, stream>>>(js);
  }

  auto QJ = [&](const bf16_t* A, int wq, int wk, int wv,
                const float* bq, const float* bk, const float* bv2,
                const bf16_t* Ak){
    QkvJob j; j.A = A;
    j.Wt0 = Wa+o_w[wq]; j.Wt1 = Wa+o_w[wk]; j.Wt2 = Wa+o_w[wv];
    j.b0 = bq; j.b1 = bk; j.b2 = bv2;
    j.C0 = H0; j.C1 = H1; j.C2 = H2; j.qs = QS;
    (void)Ak; return j;
  };

  // ---- encoder ----
  {
    QkvJob j = QJ(P0, 0,1,2, F(10),F(12),F(14), P0);
    k_qkv<<<gG, blk, 0, stream>>>(j);
  }
  k_attn<<<gA, blk, 0, stream>>>(H0, H1, H2, valid, H0);
  k_gemm<0,3,256><<<gG, blk, 0, stream>>>(H0, Wa+o_w[3], F(16), P0, P0, F(17),F(18), NF,NF);
  k_gemm<1,0,256><<<gG, blk, 0, stream>>>(P0, Wa+o_w[4], F(20), H0, NB,NF,NF,NF,NF);
  k_gemm<0,3,256><<<gG, blk, 0, stream>>>(H0, Wa+o_w[5], F(22), P0, P0, F(23),F(24), NF,NF);

  // ---- decoder self-attention ----
  {
    QkvJob j = QJ(P1, 6,7,8, F(26),F(28),F(30), P1);
    k_qkv<<<gG, blk, 0, stream>>>(j);
  }
  k_attn<<<gA, blk, 0, stream>>>(H0, H1, H2, valid, H0);
  k_gemm<0,3,256><<<gG, blk, 0, stream>>>(H0, Wa+o_w[9], F(32), P1, P1, d_ln1g,d_ln1b, NF,NF);

  // ---- decoder cross-attention: Q from P1, K/V from P0 ----
  {
    k_gemm<0,0,256><<<gG, blk, 0, stream>>>(P1, Wa+o_w[10], d_eqb, H0, NB,NF,NF,NF,NF);
    GemmJobs js;
    js.j[0] = { P0, Wa+o_w[11], d_ekb, H1, 0, 1.0f };
    js.j[1] = { P0, Wa+o_w[12], d_evb, H2, 2, 1.0f };
    js.j[2] = js.j[0];
    k_gemm3<256><<<dim3(Mm/64,2), blk, 0, stream>>>(js);
  }
  k_attn<<<gA, blk, 0, stream>>>(H0, H1, H2, valid, H0);
  k_gemm<0,3,256><<<gG, blk, 0, stream>>>(H0, Wa+o_w[13], d_eob, P1, P1, F(43),F(44), NF,NF);

  // ---- decoder FFN + fused ln3 + logits ----
  k_gemm<1,0,256><<<gG, blk, 0, stream>>>(P1, Wa+o_w[14], F(46), H0, NB,NF,NF,NF,NF);
  k_gemm<0,5,256><<<gG, blk, 0, stream>>>(H0, Wa+o_w[15], F(48), logits, P1, F(49),F(50), F(51),F(52));

  k_final<<<dim3(Bb), blk, 0, stream>>>(logits, valid, out);
  #undef F
}

// Round 6
// 929.581 us; speedup vs baseline: 1.9873x; 1.2119x over previous
//
#include <hip/hip_runtime.h>
#include <hip/hip_bf16.h>

// ============================================================================
// TransformerChoiceNet forward. Round 20: weight-resident barrier-free GEMM.
// k_wgemm: full W (N=256,K<=256 -> <=128KB) staged once into LDS (frag-blocked,
// conflict-free), then waves free-run: A-frags global->reg (prefetch 1 kc),
// 16 ds_read_b128 + 32 MFMA per kc, no main-loop barriers, wave-local LN/logit
// epilogues (no cross-wave reduce). Replaces k_gemm/k_gemm3/k_qkv.
// k_attn / k_prep / k_ln0 / k_final identical to r16 (1019us baseline).
// B=128 S=512 D=64 H=256 NH=8 HD=32, M=B*S=65536.
// ============================================================================

#define Bb  128
#define Ss  512
#define Hh  256
#define NHh 8
#define Mm  (Bb*Ss)

typedef unsigned short bf16_t;
typedef __attribute__((ext_vector_type(8))) short short8;
typedef __attribute__((ext_vector_type(4))) float f32x4;

__device__ __forceinline__ float bf2f(bf16_t h){
  union { unsigned int u; float f; } v; v.u = ((unsigned int)h)<<16; return v.f;
}
__device__ __forceinline__ bf16_t f2bf(float f){
  union { float f; unsigned int u; } v; v.f = f;
  unsigned int r = (v.u + 0x7fffu + ((v.u>>16)&1u)) >> 16;   // RNE
  return (bf16_t)r;
}
__device__ __forceinline__ unsigned pk_bf16(float a, float b){  // packed RNE cvt
  union { __hip_bfloat162 h; unsigned u; } v;
  v.h = __float22bfloat162_rn(float2{a,b});
  return v.u;
}
__device__ __forceinline__ short8 ld_bf8(const bf16_t* p){   // 16B load
  union { uint4 u; short8 s; } v; v.u = *(const uint4*)p; return v.s;
}
__device__ __forceinline__ void gload16(const bf16_t* g, bf16_t* l){
  __builtin_amdgcn_global_load_lds(
      (const __attribute__((address_space(1))) void*)g,
      (__attribute__((address_space(3))) void*)l, 16, 0, 0);
}
__device__ __forceinline__ float exp2_hw(float x){           // native 2^x
  float r; asm("v_exp_f32 %0, %1" : "=v"(r) : "v"(x)); return r;
}
__device__ __forceinline__ float gelu_f(float x){
  // NewGELU; tanh via native exp + rcp: tanh(u) = 1 - 2/(e^{2u}+1)
  float u = 0.7978845608028654f*(x + 0.044715f*x*x*x);
  float e = __expf(2.0f*u);
  float th = 1.0f - 2.0f*__builtin_amdgcn_rcpf(e + 1.0f);
  return 0.5f*x*(1.0f + th);
}

// ---------------- weight prep: fp32 W[k][n] -> bf16 Wt[n][k] ------------------
struct PrepDesc { const float* s; unsigned off; int K; };
struct Prep18  { PrepDesc d[18]; };

__global__ __launch_bounds__(256) void k_prep(Prep18 p, bf16_t* __restrict__ arena)
{
  PrepDesc dd = p.d[blockIdx.y];
  int i = blockIdx.x*256 + threadIdx.x;
  if (i < dd.K*256){
    int k = i>>8, n = i&255;
    arena[dd.off + n*dd.K + k] = f2bf(dd.s[i]);
  }
}

// ---------------- LN0 (two gains) + valid mask; bf16 out ----------------------
__global__ __launch_bounds__(256) void k_ln0(const float* __restrict__ src,
    const float* __restrict__ gs, const float* __restrict__ bs,
    const float* __restrict__ gt, const float* __restrict__ bt,
    bf16_t* __restrict__ xs, bf16_t* __restrict__ xt, float* __restrict__ valid)
{
  int row  = blockIdx.x*4 + (threadIdx.x>>6);
  int lane = threadIdx.x & 63;
  float x = src[(size_t)row*64 + lane];
  float s = x;
  #pragma unroll
  for (int o=32;o>0;o>>=1) s += __shfl_xor(s,o);
  float mean = s*(1.0f/64.0f);
  float d = x - mean;
  float ss = d*d;
  #pragma unroll
  for (int o=32;o>0;o>>=1) ss += __shfl_xor(ss,o);
  float r = rsqrtf(ss*(1.0f/64.0f) + 1e-5f);
  float xn = d*r;
  xs[(size_t)row*64+lane] = f2bf(xn*gs[lane] + bs[lane]);
  xt[(size_t)row*64+lane] = f2bf(xn*gt[lane] + bt[lane]);
  if (lane==0) valid[row] = (s != 0.0f) ? 1.0f : 0.0f;
}

// ---------------- weight-resident GEMM, barrier-free main loop ----------------
// Block = 512 thr (8 waves), grid = 256 blocks, 256 rows/block, 32 rows/wave.
// W fully LDS-resident, frag-blocked: Ws[(kc*16+nt)*512 + lane*8].
// OUTM: 0 bf16 C[M,256] (EPI 0=id(*cs) / 1=gelu) | 2 bf16 VT[b][n][s] |
//       3 LN(Pres+(acc+b)) -> bf16 | 5 LN -> dot outW -> fp32 logits.
template<int EPI, int OUTM, int KK>
__global__ __launch_bounds__(512,2) void k_wgemm(const bf16_t* __restrict__ A,
    const bf16_t* __restrict__ Wt, const float* __restrict__ bias,
    void* __restrict__ Cv, const bf16_t* __restrict__ Pres,
    const float* __restrict__ g, const float* __restrict__ bb,
    const float* __restrict__ oW, const float* __restrict__ obp, float cs)
{
  constexpr int NKC  = KK/32;       // 8 (K=256) or 2 (K=64)
  constexpr int IDS  = 16*NKC;      // frag blocks
  constexpr int PERW = IDS/8;
  __shared__ bf16_t Ws[IDS*512];    // 128 KB (K=256) / 32 KB (K=64)

  int t = threadIdx.x, w = t>>6, lane = t&63, l15 = lane&15, quad = lane>>4;
  int r0 = blockIdx.x*256 + w*32;

  #pragma unroll
  for (int j=0; j<PERW; j++){       // stage FULL W once, conflict-free layout
    int id = w*PERW + j; int kc = id>>4, nt = id&15;
    gload16(Wt + (size_t)(nt*16 + l15)*KK + kc*32 + quad*8, &Ws[id*512]);
  }
  // first A frags issued before the barrier (complete during W drain)
  short8 a0 = ld_bf8(A + (size_t)(r0      + l15)*KK + quad*8);
  short8 a1 = ld_bf8(A + (size_t)(r0 + 16 + l15)*KK + quad*8);
  __syncthreads();                  // ONLY barrier in the kernel

  f32x4 z = {0.f,0.f,0.f,0.f};
  f32x4 acc0[16], acc1[16];
  #pragma unroll
  for (int nt=0; nt<16; nt++){ acc0[nt] = z; acc1[nt] = z; }

  #pragma unroll
  for (int kc=0; kc<NKC; kc++){
    short8 a0n, a1n;
    if (kc+1 < NKC){                // prefetch next kc's A frags (L3-resident)
      a0n = ld_bf8(A + (size_t)(r0      + l15)*KK + (kc+1)*32 + quad*8);
      a1n = ld_bf8(A + (size_t)(r0 + 16 + l15)*KK + (kc+1)*32 + quad*8);
    }
    #pragma unroll
    for (int nt=0; nt<16; nt++){
      short8 b = ld_bf8(&Ws[(kc*16 + nt)*512 + lane*8]);
      acc0[nt] = __builtin_amdgcn_mfma_f32_16x16x32_bf16(a0, b, acc0[nt], 0,0,0);
      acc1[nt] = __builtin_amdgcn_mfma_f32_16x16x32_bf16(a1, b, acc1[nt], 0,0,0);
    }
    a0 = a0n; a1 = a1n;
  }

  float bv[16];
  #pragma unroll
  for (int nt=0; nt<16; nt++) bv[nt] = bias[nt*16 + l15];

  if (OUTM==0){
    auto epi = [&](f32x4 (&ac)[16], int tt){
      int rowb = r0 + tt*16 + quad*4;
      #pragma unroll
      for (int nt=0; nt<16; nt++)
        #pragma unroll
        for (int r=0; r<4; r++){
          float v = ac[nt][r] + bv[nt];
          v = (EPI==1) ? gelu_f(v) : v*cs;
          ((bf16_t*)Cv)[(size_t)(rowb + r)*256 + nt*16 + l15] = f2bf(v);
        }
    };
    epi(acc0, 0); epi(acc1, 1);
  } else if (OUTM==2){
    auto epi = [&](f32x4 (&ac)[16], int tt){
      int m = r0 + tt*16 + quad*4;
      #pragma unroll
      for (int nt=0; nt<16; nt++){
        int col = nt*16 + l15;
        uint2 pk = { pk_bf16(ac[nt][0]+bv[nt], ac[nt][1]+bv[nt]),
                     pk_bf16(ac[nt][2]+bv[nt], ac[nt][3]+bv[nt]) };
        *(uint2*)&((bf16_t*)Cv)[((size_t)((m>>9)*256 + col))*512 + (m&511)] = pk;
      }
    };
    epi(acc0, 0); epi(acc1, 1);
  } else {
    float gv[16], bbv[16], wv[16];
    #pragma unroll
    for (int nt=0; nt<16; nt++){ gv[nt] = g[nt*16+l15]; bbv[nt] = bb[nt*16+l15]; }
    if (OUTM==5)
      #pragma unroll
      for (int nt=0; nt<16; nt++) wv[nt] = oW[nt*16+l15];
    float ob0 = (OUTM==5) ? obp[0] : 0.f;

    auto epi = [&](f32x4 (&ac)[16], int tt){
      #pragma unroll
      for (int r=0; r<4; r++){
        int row = r0 + tt*16 + quad*4 + r;
        const bf16_t* pr = Pres + (size_t)row*256;
        float v[16]; float s = 0.f, q = 0.f;
        #pragma unroll
        for (int nt=0; nt<16; nt++){
          v[nt] = ac[nt][r] + bv[nt] + bf2f(pr[nt*16 + l15]);
          s += v[nt]; q += v[nt]*v[nt];
        }
        s += __shfl_xor(s,1); s += __shfl_xor(s,2);
        s += __shfl_xor(s,4); s += __shfl_xor(s,8);
        q += __shfl_xor(q,1); q += __shfl_xor(q,2);
        q += __shfl_xor(q,4); q += __shfl_xor(q,8);
        float mean = s*(1.0f/256.0f);
        float var  = q*(1.0f/256.0f) - mean*mean;
        float rstd = rsqrtf(var + 1e-5f);
        if (OUTM==3){
          bf16_t* po = (bf16_t*)Cv + (size_t)row*256;
          #pragma unroll
          for (int nt=0; nt<16; nt++)
            po[nt*16 + l15] = f2bf((v[nt]-mean)*rstd*gv[nt] + bbv[nt]);
        } else {
          float s2 = 0.f;
          #pragma unroll
          for (int nt=0; nt<16; nt++)
            s2 += ((v[nt]-mean)*rstd*gv[nt] + bbv[nt]) * wv[nt];
          s2 += __shfl_xor(s2,1); s2 += __shfl_xor(s2,2);
          s2 += __shfl_xor(s2,4); s2 += __shfl_xor(s2,8);
          if (l15==0) ((float*)Cv)[row] = s2 + ob0;
        }
      }
    };
    epi(acc0, 0); epi(acc1, 1);
  }
}

// ---------------- MFMA attention (r16: remap + exp2 + setprio) ----------------
__global__ __launch_bounds__(256) void k_attn(const bf16_t* __restrict__ Qm,
    const bf16_t* __restrict__ Km, const bf16_t* __restrict__ VT,
    const float* __restrict__ valid, bf16_t* __restrict__ AO)
{
  __shared__ bf16_t Pbuf[4][2][2][16][40];   // [wave][qtile][slot][q][key] 20 KB
  __shared__ float  Smask[512];              // 0 or -1e10*log2e
  int t = threadIdx.x, wave = t>>6, lane = t&63, l15 = lane&15, quad = lane>>4;
  int lid = blockIdx.x + 8*blockIdx.y + 1024*blockIdx.z;    // dispatch order
  int hp = lid & 3, pb = (lid>>2)&1, g = (lid>>3)&7, bh = lid>>6;
  int h  = hp*2 + (g&1);          // head: pair hp, parity from g
  int qc = g>>1;
  int b  = bh*2 + pb;
  int q0 = qc*128;

  Smask[t]     = (valid[b*Ss + t      ] != 0.f) ? 0.f : -1.44269504e10f;
  Smask[t+256] = (valid[b*Ss + t + 256] != 0.f) ? 0.f : -1.44269504e10f;
  __syncthreads();

  short8 aQ0 = ld_bf8(Qm + (size_t)(b*Ss + q0 + (wave*2  )*16 + l15)*256 + h*32 + quad*8);
  short8 aQ1 = ld_bf8(Qm + (size_t)(b*Ss + q0 + (wave*2+1)*16 + l15)*256 + h*32 + quad*8);
  const bf16_t* Kb = Km + (size_t)(b*Ss)*256 + h*32;          // + key*256
  const bf16_t* Vb = VT + ((size_t)b*256 + h*32)*512;         // + d*512 + key

  f32x4 z = {0.f,0.f,0.f,0.f};
  f32x4 O0[2] = {z,z}, O1[2] = {z,z};
  float ls0 = 0.f, ls1 = 0.f;

  auto process = [&](int kt2n, short8 K0, short8 K1){
    int s = kt2n & 1;
    #pragma unroll
    for (int half=0; half<2; half++){
      short8 aK = half ? K1 : K0;
      int ktile = kt2n*2 + half;
      __builtin_amdgcn_s_setprio(1);
      f32x4 s0 = __builtin_amdgcn_mfma_f32_16x16x32_bf16(aK, aQ0, z, 0,0,0);
      f32x4 s1 = __builtin_amdgcn_mfma_f32_16x16x32_bf16(aK, aQ1, z, 0,0,0);
      __builtin_amdgcn_s_setprio(0);
      float4 mb = *(const float4*)&Smask[ktile*16 + quad*4];
      float p00 = exp2_hw(s0[0] + mb.x);    // Q pre-scaled by QS*log2e
      float p01 = exp2_hw(s0[1] + mb.y);
      float p02 = exp2_hw(s0[2] + mb.z);
      float p03 = exp2_hw(s0[3] + mb.w);
      float p10 = exp2_hw(s1[0] + mb.x);
      float p11 = exp2_hw(s1[1] + mb.y);
      float p12 = exp2_hw(s1[2] + mb.z);
      float p13 = exp2_hw(s1[3] + mb.w);
      ls0 += (p00+p01)+(p02+p03);
      ls1 += (p10+p11)+(p12+p13);
      uint2 w0 = { pk_bf16(p00,p01), pk_bf16(p02,p03) };
      uint2 w1 = { pk_bf16(p10,p11), pk_bf16(p12,p13) };
      *(uint2*)&Pbuf[wave][0][s][l15][half*16 + quad*4] = w0;
      *(uint2*)&Pbuf[wave][1][s][l15][half*16 + quad*4] = w1;
    }
  };
  auto loadK = [&](int n, short8& K0, short8& K1){
    K0 = ld_bf8(Kb + (size_t)((n*2  )*16 + l15)*256 + quad*8);
    K1 = ld_bf8(Kb + (size_t)((n*2+1)*16 + l15)*256 + quad*8);
  };
  auto loadV = [&](int n, short8& V0, short8& V1){
    V0 = ld_bf8(Vb + (size_t)(l15   )*512 + n*32 + quad*8);
    V1 = ld_bf8(Vb + (size_t)(16+l15)*512 + n*32 + quad*8);
  };

  short8 cK0, cK1, pK0, pK1, nK0, nK1;
  short8 cV0, cV1, mV0, mV1, nV0, nV1;
  loadK(0, cK0, cK1);
  process(0, cK0, cK1);
  loadK(1, pK0, pK1);
  loadV(0, cV0, cV1);
  loadV(1, mV0, mV1);

  #pragma unroll 2
  for (int kt2=0; kt2<16; kt2++){
    if (kt2+2 < 16){ loadK(kt2+2, nK0, nK1); loadV(kt2+2, nV0, nV1); }
    int s = kt2 & 1;
    short8 aP0 = ld_bf8(&Pbuf[wave][0][s][l15][quad*8]);
    short8 aP1 = ld_bf8(&Pbuf[wave][1][s][l15][quad*8]);
    __builtin_amdgcn_s_setprio(1);
    O0[0] = __builtin_amdgcn_mfma_f32_16x16x32_bf16(aP0, cV0, O0[0], 0,0,0);
    O0[1] = __builtin_amdgcn_mfma_f32_16x16x32_bf16(aP0, cV1, O0[1], 0,0,0);
    O1[0] = __builtin_amdgcn_mfma_f32_16x16x32_bf16(aP1, cV0, O1[0], 0,0,0);
    O1[1] = __builtin_amdgcn_mfma_f32_16x16x32_bf16(aP1, cV1, O1[1], 0,0,0);
    __builtin_amdgcn_s_setprio(0);
    if (kt2+1 < 16) process(kt2+1, pK0, pK1);
    pK0 = nK0; pK1 = nK1;
    cV0 = mV0; cV1 = mV1; mV0 = nV0; mV1 = nV1;
  }

  ls0 += __shfl_xor(ls0,16); ls0 += __shfl_xor(ls0,32);
  ls1 += __shfl_xor(ls1,16); ls1 += __shfl_xor(ls1,32);
  float linv0 = (ls0 > 0.f) ? 1.0f/ls0 : 0.f;
  float linv1 = (ls1 > 0.f) ? 1.0f/ls1 : 0.f;
  float i0[4], i1[4];
  #pragma unroll
  for (int r=0; r<4; r++){
    i0[r] = __shfl(linv0, quad*4 + r);
    i1[r] = __shfl(linv1, quad*4 + r);
  }
  size_t r0 = (size_t)(b*Ss + q0 + (wave*2  )*16);
  size_t r1 = (size_t)(b*Ss + q0 + (wave*2+1)*16);
  #pragma unroll
  for (int nt=0; nt<2; nt++)
    #pragma unroll
    for (int r=0; r<4; r++){
      AO[(r0 + quad*4 + r)*256 + h*32 + nt*16 + l15] = f2bf(O0[nt][r]*i0[r]);
      AO[(r1 + quad*4 + r)*256 + h*32 + nt*16 + l15] = f2bf(O1[nt][r]*i1[r]);
    }
}

// ---------------- final: p = exp(logits)*valid, normalize per batch -----------
__global__ __launch_bounds__(256) void k_final(const float* __restrict__ L,
    const float* __restrict__ valid, float* __restrict__ out)
{
  __shared__ float wsum[4];
  int b = blockIdx.x, t = threadIdx.x;
  float e0 = __expf(L[b*Ss + t      ]) * valid[b*Ss + t      ];
  float e1 = __expf(L[b*Ss + 256 + t]) * valid[b*Ss + 256 + t];
  float s = e0 + e1;
  #pragma unroll
  for (int o=32;o>0;o>>=1) s += __shfl_xor(s,o);
  if ((t&63)==0) wsum[t>>6] = s;
  __syncthreads();
  float tot = wsum[0]+wsum[1]+wsum[2]+wsum[3];
  out[b*Ss + t      ] = e0/tot;
  out[b*Ss + 256 + t] = e1/tot;
}

// ============================================================================
extern "C" void kernel_launch(void* const* d_in, const int* in_sizes, int n_in,
                              void* d_out, int out_size, void* d_ws, size_t ws_size,
                              hipStream_t stream)
{
  #define F(i) ((const float*)d_in[(i)])
  bool sig = (in_sizes[33] == 256);   // signature order vs dict order
  const float* d_eqW  = F(sig?35:33); const float* d_eqb  = F(sig?36:34);
  const float* d_ekW  = F(sig?37:35); const float* d_ekb  = F(sig?38:36);
  const float* d_evW  = F(sig?39:37); const float* d_evb  = F(sig?40:38);
  const float* d_eoW  = F(sig?41:39); const float* d_eob  = F(sig?42:40);
  const float* d_ln1g = F(sig?33:41); const float* d_ln1b = F(sig?34:42);

  // ---- workspace (~163 MiB) ----
  char* w = (char*)d_ws;
  bf16_t* P0 = (bf16_t*)w; w += (size_t)Mm*Hh*2;   // 32 MiB residual (enc)
  bf16_t* P1 = (bf16_t*)w; w += (size_t)Mm*Hh*2;   // 32 MiB residual (dec)
  bf16_t* H0 = (bf16_t*)w; w += (size_t)Mm*Hh*2;   // 32 MiB Q / AO / gelu
  bf16_t* H1 = (bf16_t*)w;                          // 32 MiB K / xs alias
  bf16_t* xs = (bf16_t*)w; w += (size_t)Mm*Hh*2;
  bf16_t* H2 = (bf16_t*)w;                          // 32 MiB VT / xt alias
  bf16_t* xt = (bf16_t*)w; w += (size_t)Mm*Hh*2;
  bf16_t* Wa = (bf16_t*)w; w += (size_t)(2*16384 + 16*65536)*2;  // 2.1 MiB
  float*  valid  = (float*)w; w += (size_t)Mm*4;
  float*  logits = (float*)w; w += (size_t)Mm*4;
  float* out = (float*)d_out;

  unsigned o_sem = 0, o_tem = 16384;
  unsigned o_w[16]; for (int i=0;i<16;i++) o_w[i] = 32768 + i*65536u;
  Prep18 pp;
  const float* srcs[18] = { F(5), F(7), F(9), F(11), F(13), F(15), F(19), F(21),
                            F(25), F(27), F(29), F(31), d_eqW, d_ekW, d_evW, d_eoW,
                            F(45), F(47) };
  unsigned offs[18] = { o_sem, o_tem, o_w[0],o_w[1],o_w[2],o_w[3],o_w[4],o_w[5],
                        o_w[6],o_w[7],o_w[8],o_w[9],o_w[10],o_w[11],o_w[12],o_w[13],
                        o_w[14],o_w[15] };
  for (int i=0;i<18;i++){ pp.d[i].s = srcs[i]; pp.d[i].off = offs[i]; pp.d[i].K = (i<2)?64:256; }

  dim3 blk(256);
  dim3 blk512(512);
  dim3 gLN(Mm/4);
  dim3 gW(256);                     // 256 rows/block
  dim3 gA(NHh, Bb, 4);
  dim3 gP(256, 18);
  const float* NF = nullptr; const bf16_t* NB = nullptr;
  // 1/sqrt(32) * log2(e) folded into Q so attention uses native exp2
  const float QS = 0.17677669529663687f * 1.4426950408889634f;

  k_prep<<<gP, blk, 0, stream>>>(pp, Wa);
  k_ln0<<<gLN, blk, 0, stream>>>(F(0), F(1),F(2), F(3),F(4), xs, xt, valid);

  // emb pair (K=64)
  k_wgemm<0,0,64><<<gW, blk512, 0, stream>>>(xs, Wa+o_sem, F(6), P0, NB, NF,NF,NF,NF, 1.0f);
  k_wgemm<0,0,64><<<gW, blk512, 0, stream>>>(xt, Wa+o_tem, F(8), P1, NB, NF,NF,NF,NF, 1.0f);

  // ---- encoder ----
  k_wgemm<0,0,256><<<gW, blk512, 0, stream>>>(P0, Wa+o_w[0], F(10), H0, NB, NF,NF,NF,NF, QS);
  k_wgemm<0,0,256><<<gW, blk512, 0, stream>>>(P0, Wa+o_w[1], F(12), H1, NB, NF,NF,NF,NF, 1.0f);
  k_wgemm<0,2,256><<<gW, blk512, 0, stream>>>(P0, Wa+o_w[2], F(14), H2, NB, NF,NF,NF,NF, 1.0f);
  k_attn<<<gA, blk, 0, stream>>>(H0, H1, H2, valid, H0);
  k_wgemm<0,3,256><<<gW, blk512, 0, stream>>>(H0, Wa+o_w[3], F(16), P0, P0, F(17),F(18), NF,NF, 1.0f);
  k_wgemm<1,0,256><<<gW, blk512, 0, stream>>>(P0, Wa+o_w[4], F(20), H0, NB, NF,NF,NF,NF, 1.0f);
  k_wgemm<0,3,256><<<gW, blk512, 0, stream>>>(H0, Wa+o_w[5], F(22), P0, P0, F(23),F(24), NF,NF, 1.0f);

  // ---- decoder self-attention ----
  k_wgemm<0,0,256><<<gW, blk512, 0, stream>>>(P1, Wa+o_w[6], F(26), H0, NB, NF,NF,NF,NF, QS);
  k_wgemm<0,0,256><<<gW, blk512, 0, stream>>>(P1, Wa+o_w[7], F(28), H1, NB, NF,NF,NF,NF, 1.0f);
  k_wgemm<0,2,256><<<gW, blk512, 0, stream>>>(P1, Wa+o_w[8], F(30), H2, NB, NF,NF,NF,NF, 1.0f);
  k_attn<<<gA, blk, 0, stream>>>(H0, H1, H2, valid, H0);
  k_wgemm<0,3,256><<<gW, blk512, 0, stream>>>(H0, Wa+o_w[9], F(32), P1, P1, d_ln1g,d_ln1b, NF,NF, 1.0f);

  // ---- decoder cross-attention: Q from P1, K/V from P0 ----
  k_wgemm<0,0,256><<<gW, blk512, 0, stream>>>(P1, Wa+o_w[10], d_eqb, H0, NB, NF,NF,NF,NF, QS);
  k_wgemm<0,0,256><<<gW, blk512, 0, stream>>>(P0, Wa+o_w[11], d_ekb, H1, NB, NF,NF,NF,NF, 1.0f);
  k_wgemm<0,2,256><<<gW, blk512, 0, stream>>>(P0, Wa+o_w[12], d_evb, H2, NB, NF,NF,NF,NF, 1.0f);
  k_attn<<<gA, blk, 0, stream>>>(H0, H1, H2, valid, H0);
  k_wgemm<0,3,256><<<gW, blk512, 0, stream>>>(H0, Wa+o_w[13], d_eob, P1, P1, F(43),F(44), NF,NF, 1.0f);

  // ---- decoder FFN + fused ln3 + logits ----
  k_wgemm<1,0,256><<<gW, blk512, 0, stream>>>(P1, Wa+o_w[14], F(46), H0, NB, NF,NF,NF,NF, 1.0f);
  k_wgemm<0,5,256><<<gW, blk512, 0, stream>>>(H0, Wa+o_w[15], F(48), logits, P1, F(49),F(50), F(51),F(52), 1.0f);

  k_final<<<dim3(Bb), blk, 0, stream>>>(logits, valid, out);
  #undef F
}